// Round 5
// baseline (871.041 us; speedup 1.0000x reference)
//
#include <hip/hip_runtime.h>
#include <hip/hip_bf16.h>
#include <cstdint>

typedef float f32x4 __attribute__((ext_vector_type(4)));
typedef short short8v __attribute__((ext_vector_type(8)));

#define ATT 256
#define D_IN 512

static __device__ __forceinline__ unsigned short f2bf(float x) {
    return __builtin_bit_cast(unsigned short, __float2bfloat16(x));
}
static __device__ __forceinline__ float bf2f(unsigned short us) {
    return __builtin_bit_cast(float, (uint32_t)us << 16);
}
// exact identity tanh(x) = 1 - 2/(1+e^{2x}); saturates cleanly at +-1
static __device__ __forceinline__ float fast_tanhf(float x) {
    return 1.0f - 2.0f / (1.0f + __expf(2.0f * x));
}

// ---------------------------------------------------------------------------
// Pre-kernel: W [512][256] fp32 -> bf16 in B-fragment order:
//   o = ((ks*16 + nt)*64 + lane)*8 + j  holds  W[ks*32 + hi*8 + j][nt*16 + lo]
// ---------------------------------------------------------------------------
__global__ void wconv_kernel(const float* __restrict__ W, unsigned short* __restrict__ Wf) {
    int o = blockIdx.x * 256 + threadIdx.x;      // 0 .. 131071
    int j  = o & 7;
    int ln = (o >> 3) & 63;
    int nt = (o >> 9) & 15;
    int ks = o >> 13;
    int hi = ln >> 4, lo = ln & 15;
    Wf[o] = f2bf(W[(ks * 32 + hi * 8 + j) * ATT + nt * 16 + lo]);
}

// ---------------------------------------------------------------------------
// Main kernel: 1024 threads = 16 waves; tile = 64 rows (16 samples).
// Wave w owns output columns [w*16, w*16+16): B-frags = 16 x short8v = 64 VGPR.
// Xs double-buffered bf16 in LDS (2 x 64 KB, XOR swizzle). Next tile's X
// loaded in 4 quarter-chunks interleaved with the k-loop quarters (8 VGPR
// staging window). VGPR hard cap 128 (16 waves/CU = 4/SIMD).
// ---------------------------------------------------------------------------
__global__ __launch_bounds__(1024) void att_main(
    const float* __restrict__ X, const unsigned short* __restrict__ Wf,
    const float* __restrict__ bb, const float* __restrict__ uu,
    float* __restrict__ out, float* __restrict__ alph,
    int ntiles, int tpb)
{
    __shared__ __align__(16) unsigned short Xs[2][64 * 512];  // 2 x 64 KB
    __shared__ __align__(16) float vured[16][64];             // 4 KB
    __shared__ float alsh[64];

    const int tid  = threadIdx.x;
    const int wid  = tid >> 6;                   // 0..15 = nt owned by this wave
    const int lane = tid & 63;
    const int lo   = lane & 15, hi = lane >> 4;

    const int tile0 = blockIdx.x * tpb;
    if (tile0 >= ntiles) return;

    // ---- B fragments: resident for the whole block (64 VGPR) ----
    short8v B[16];
    {
        const short8v* Wp = (const short8v*)Wf + lane;
        #pragma unroll
        for (int ks = 0; ks < 16; ++ks)
            B[ks] = Wp[(ks * 16 + wid) * 64];
    }
    const int ccol = wid * 16 + lo;
    const float bv = bb[ccol], uv = uu[ccol];

    // ---- prologue: stage tile0 into Xs[0] ----
    {
        const float4* Xg = (const float4*)(X + (int64_t)tile0 * 64 * D_IN);
        #pragma unroll
        for (int q = 0; q < 4; ++q) {
            int g = tid + q * 1024;              // granule: 8 fp32 -> 8 bf16 (16 B)
            int row = g >> 6, c8 = g & 63;
            float4 va = Xg[row * 128 + c8 * 2 + 0];
            float4 vb = Xg[row * 128 + c8 * 2 + 1];
            short8v pk;
            pk[0] = (short)f2bf(va.x); pk[1] = (short)f2bf(va.y);
            pk[2] = (short)f2bf(va.z); pk[3] = (short)f2bf(va.w);
            pk[4] = (short)f2bf(vb.x); pk[5] = (short)f2bf(vb.y);
            pk[6] = (short)f2bf(vb.z); pk[7] = (short)f2bf(vb.w);
            int boff = (row * 1024 + c8 * 16) ^ ((row & 7) << 4);
            *(short8v*)((char*)Xs[0] + boff) = pk;
        }
    }
    __syncthreads();

    int curb = 0;
    for (int i = 0; i < tpb; ++i) {
        const int tile = tile0 + i;
        if (tile >= ntiles) break;
        const bool havenext = (i + 1 < tpb) && (tile + 1 < ntiles);
        const unsigned short* XsC = Xs[curb];
        unsigned short* XsN = Xs[curb ^ 1];
        const float4* Xg1 = (const float4*)(X + (int64_t)(tile + 1) * 64 * D_IN);

        f32x4 acc[4];
        #pragma unroll
        for (int rt = 0; rt < 4; ++rt) acc[rt] = (f32x4){0.f, 0.f, 0.f, 0.f};

        // ---- K-loop in 4 quarters; next-tile staging interleaved ----
        #pragma unroll
        for (int q = 0; q < 4; ++q) {
            float4 va, vb;
            int srow = 0, sc8 = 0;
            if (havenext) {
                int g = tid + q * 1024;
                srow = g >> 6; sc8 = g & 63;
                va = Xg1[srow * 128 + sc8 * 2 + 0];
                vb = Xg1[srow * 128 + sc8 * 2 + 1];
            }
            #pragma unroll
            for (int ks2 = 0; ks2 < 4; ++ks2) {
                int ks = q * 4 + ks2;
                #pragma unroll
                for (int rt = 0; rt < 4; ++rt) {
                    int row = rt * 16 + lo;
                    int boff = (row * 1024 + ks * 64 + hi * 16) ^ ((row & 7) << 4);
                    short8v a = *(const short8v*)((const char*)XsC + boff);
                    acc[rt] = __builtin_amdgcn_mfma_f32_16x16x32_bf16(a, B[ks], acc[rt], 0, 0, 0);
                }
            }
            if (havenext) {
                short8v pk;
                pk[0] = (short)f2bf(va.x); pk[1] = (short)f2bf(va.y);
                pk[2] = (short)f2bf(va.z); pk[3] = (short)f2bf(va.w);
                pk[4] = (short)f2bf(vb.x); pk[5] = (short)f2bf(vb.y);
                pk[6] = (short)f2bf(vb.z); pk[7] = (short)f2bf(vb.w);
                int boff = (srow * 1024 + sc8 * 16) ^ ((srow & 7) << 4);
                *(short8v*)((char*)XsN + boff) = pk;
            }
        }

        // ---- epilogue 1: tanh + u-dot partials, butterfly over 16 col-lanes ----
        float p[4][4];
        #pragma unroll
        for (int rt = 0; rt < 4; ++rt)
            #pragma unroll
            for (int r = 0; r < 4; ++r)
                p[rt][r] = fast_tanhf(acc[rt][r] + bv) * uv;
        #pragma unroll
        for (int m = 1; m < 16; m <<= 1)
            #pragma unroll
            for (int rt = 0; rt < 4; ++rt)
                #pragma unroll
                for (int r = 0; r < 4; ++r)
                    p[rt][r] += __shfl_xor(p[rt][r], m, 64);
        if (lo == 0) {
            #pragma unroll
            for (int rt = 0; rt < 4; ++rt) {
                f32x4 v4 = {p[rt][0], p[rt][1], p[rt][2], p[rt][3]};
                *(f32x4*)&vured[wid][rt * 16 + hi * 4] = v4;
            }
        }
        __syncthreads();

        // ---- epilogue 2: cross-wave vu reduce + softmax over t (quads) ----
        if (tid < 64) {
            float v = 0.f;
            #pragma unroll
            for (int w = 0; w < 16; ++w) v += vured[w][tid];
            float mx = fmaxf(v, __shfl_xor(v, 1, 64));
            mx = fmaxf(mx, __shfl_xor(mx, 2, 64));
            float e = __expf(v - mx);
            float ss = e + __shfl_xor(e, 1, 64);
            ss += __shfl_xor(ss, 2, 64);
            float av = e / ss;
            alsh[tid] = av;
            alph[(int64_t)tile * 64 + tid] = av;
        }
        __syncthreads();

        // ---- epilogue 3: weighted sum; wave w handles sample s = w ----
        {
            const int s = wid;
            float a0 = alsh[s * 4 + 0], a1 = alsh[s * 4 + 1];
            float a2 = alsh[s * 4 + 2], a3 = alsh[s * 4 + 3];
            float* outp = out + ((int64_t)tile * 16 + s) * D_IN;
            float o[8];
            #pragma unroll
            for (int e = 0; e < 8; ++e) o[e] = 0.f;
            #pragma unroll
            for (int r = 0; r < 4; ++r) {
                int row = s * 4 + r;
                int boff = (row * 1024 + lane * 16) ^ ((row & 7) << 4);
                short8v xq = *(const short8v*)((const char*)XsC + boff);
                float ar = (r == 0) ? a0 : (r == 1) ? a1 : (r == 2) ? a2 : a3;
                #pragma unroll
                for (int e = 0; e < 8; ++e)
                    o[e] += ar * bf2f((unsigned short)xq[e]);
            }
            float4 o4a = {o[0], o[1], o[2], o[3]};
            float4 o4b = {o[4], o[5], o[6], o[7]};
            *(float4*)(outp + lane * 8 + 0) = o4a;
            *(float4*)(outp + lane * 8 + 4) = o4b;
        }
        __syncthreads();   // stage writes visible; vured/alsh/Xs reusable
        curb ^= 1;
    }
}

// ---------------------------------------------------------------------------
// Fallback (generality): plain fp32, 1 block per sample.
// ---------------------------------------------------------------------------
__global__ void att_fallback(const float* __restrict__ X, const float* __restrict__ W,
                             const float* __restrict__ bb, const float* __restrict__ uu,
                             float* __restrict__ out, float* __restrict__ alph)
{
    const int s = blockIdx.x;
    const int tid = threadIdx.x;                   // 256 threads
    __shared__ float Xsf[2048];
    __shared__ float red[4][4];
    __shared__ float alshf[4];
    for (int i = tid; i < 2048; i += 256) Xsf[i] = X[(size_t)s * 2048 + i];
    __syncthreads();
    float vus[4];
    const int a = tid;
    for (int t = 0; t < 4; ++t) {
        float acc = bb[a];
        for (int d = 0; d < 512; ++d) acc += Xsf[t * 512 + d] * W[d * 256 + a];
        vus[t] = tanhf(acc) * uu[a];
    }
    const int wid = tid >> 6, lane = tid & 63;
    for (int t = 0; t < 4; ++t) {
        float v = vus[t];
        for (int m = 1; m < 64; m <<= 1) v += __shfl_xor(v, m, 64);
        if (lane == 0) red[t][wid] = v;
    }
    __syncthreads();
    if (tid == 0) {
        float vv[4];
        for (int t = 0; t < 4; ++t) vv[t] = red[t][0] + red[t][1] + red[t][2] + red[t][3];
        float mx = fmaxf(fmaxf(vv[0], vv[1]), fmaxf(vv[2], vv[3]));
        float e[4], ssum = 0.f;
        for (int t = 0; t < 4; ++t) { e[t] = expf(vv[t] - mx); ssum += e[t]; }
        for (int t = 0; t < 4; ++t) {
            float av = e[t] / ssum;
            alshf[t] = av;
            alph[(size_t)s * 4 + t] = av;
        }
    }
    __syncthreads();
    for (int d = tid; d < 512; d += 256) {
        float o = 0.f;
        for (int t = 0; t < 4; ++t) o += alshf[t] * Xsf[t * 512 + d];
        out[(size_t)s * 512 + d] = o;
    }
}

// ---------------------------------------------------------------------------
extern "C" void kernel_launch(void* const* d_in, const int* in_sizes, int n_in,
                              void* d_out, int out_size, void* d_ws, size_t ws_size,
                              hipStream_t stream) {
    const float* X = (const float*)d_in[0];
    const float* W = (const float*)d_in[1];
    const float* b = (const float*)d_in[2];
    const float* u = (const float*)d_in[3];
    float* out = (float*)d_out;
    const int N = in_sizes[0] / (4 * D_IN);        // samples
    float* alph = out + (size_t)N * D_IN;

    if (ws_size >= (size_t)D_IN * ATT * sizeof(unsigned short) && (N % 16) == 0) {
        unsigned short* Wf = (unsigned short*)d_ws;
        wconv_kernel<<<(D_IN * ATT) / 256, 256, 0, stream>>>(W, Wf);
        const int ntiles = N / 16;                 // 64-row tiles
        const int grid = ntiles < 512 ? ntiles : 512;
        const int tpb = (ntiles + grid - 1) / grid;
        att_main<<<grid, 1024, 0, stream>>>(X, Wf, b, u, out, alph, ntiles, tpb);
    } else {
        att_fallback<<<N, 256, 0, stream>>>(X, W, b, u, out, alph);
    }
}

// Round 6
// 631.310 us; speedup vs baseline: 1.3797x; 1.3797x over previous
//
#include <hip/hip_runtime.h>
#include <hip/hip_bf16.h>
#include <cstdint>

typedef float f32x4 __attribute__((ext_vector_type(4)));
typedef short short8v __attribute__((ext_vector_type(8)));

#define ATT 256
#define D_IN 512

static __device__ __forceinline__ unsigned short f2bf(float x) {
    return __builtin_bit_cast(unsigned short, __float2bfloat16(x));
}
static __device__ __forceinline__ float bf2f(unsigned short us) {
    return __builtin_bit_cast(float, (uint32_t)us << 16);
}
// exact identity tanh(x) = 1 - 2/(1+e^{2x}); saturates cleanly at +-1
static __device__ __forceinline__ float fast_tanhf(float x) {
    return 1.0f - 2.0f / (1.0f + __expf(2.0f * x));
}

// X-tile LDS fragment layout: element (row, k) of the 64x512 tile lives at
//   frag = (k>>5)*4 + (row>>4)          (ks-major, rt minor)
//   lane_f = (row&15) + ((k>>3)&3)*16   (== MFMA lane for A-frag)
//   j = k&7                             (position in short8v)
//   byte off = (frag*64 + lane_f)*16  XOR  ((ks&7)<<4)
static __device__ __forceinline__ int xfrag_off(int row, int c8 /*= k>>3*/) {
    int ks = c8 >> 2, rt = row >> 4;
    int lane_f = (row & 15) + (c8 & 3) * 16;
    return (((ks * 4 + rt) * 64 + lane_f) * 16) ^ ((ks & 7) << 4);
}

// ---------------------------------------------------------------------------
// Pre-kernel: W [512][256] fp32 -> bf16 in B-fragment order:
//   o = ((ks*16 + nt)*64 + lane)*8 + j  holds  W[ks*32 + hi*8 + j][nt*16 + lo]
// ---------------------------------------------------------------------------
__global__ void wconv_kernel(const float* __restrict__ W, unsigned short* __restrict__ Wf) {
    int o = blockIdx.x * 256 + threadIdx.x;      // 0 .. 131071
    int j  = o & 7;
    int ln = (o >> 3) & 63;
    int nt = (o >> 9) & 15;
    int ks = o >> 13;
    int hi = ln >> 4, lo = ln & 15;
    Wf[o] = f2bf(W[(ks * 32 + hi * 8 + j) * ATT + nt * 16 + lo]);
}

// ---------------------------------------------------------------------------
// Main kernel: 512 threads = 8 waves; tile = 64 rows (16 samples).
// Wave w owns output cols [w*32, w*32+32): B-frags = 16ks x 2nt = 128 VGPR.
// X double-buffered bf16 in LDS (2 x 64 KB, fragment order). Next tile's X
// loaded in 2 half-chunks, each issued one k-quarter before its LDS write.
// amdgpu_waves_per_eu(2,2): 2 waves/EU (forced by 130KB LDS anyway) ->
// 256-VGPR budget so B stays register-resident without spills.
// ---------------------------------------------------------------------------
__global__ __launch_bounds__(512) __attribute__((amdgpu_waves_per_eu(2, 2)))
void att_main(
    const float* __restrict__ X, const unsigned short* __restrict__ Wf,
    const float* __restrict__ bb, const float* __restrict__ uu,
    float* __restrict__ out, float* __restrict__ alph,
    int ntiles, int tpb)
{
    __shared__ __align__(16) unsigned short Xs[2][64 * 512];  // 2 x 64 KB
    __shared__ __align__(16) float vured[8][64];
    __shared__ float alsh[64];

    const int tid  = threadIdx.x;
    const int wid  = tid >> 6;                   // 0..7
    const int lane = tid & 63;
    const int lo   = lane & 15, hi = lane >> 4;
    const int lane16 = lane * 16;

    const int tile0 = blockIdx.x * tpb;
    if (tile0 >= ntiles) return;

    // ---- B fragments: resident for the whole block (128 VGPR) ----
    short8v B[16][2];
    {
        const short8v* Wp = (const short8v*)Wf + lane;
        #pragma unroll
        for (int ks = 0; ks < 16; ++ks)
            #pragma unroll
            for (int n = 0; n < 2; ++n)
                B[ks][n] = Wp[(ks * 16 + wid * 2 + n) * 64];
    }
    float bv[2], uv[2];
    #pragma unroll
    for (int n = 0; n < 2; ++n) {
        int c = wid * 32 + n * 16 + lo;
        bv[n] = bb[c];
        uv[n] = uu[c];
    }

    // ---- prologue: stage tile0 into Xs[0] (fragment order) ----
    {
        const float4* Xg = (const float4*)(X + (int64_t)tile0 * 64 * D_IN);
        #pragma unroll
        for (int it = 0; it < 8; ++it) {
            int g = tid + it * 512;              // granule of 8 fp32
            int row = g >> 6, c8 = g & 63;
            float4 va = Xg[row * 128 + c8 * 2 + 0];
            float4 vb = Xg[row * 128 + c8 * 2 + 1];
            short8v pk;
            pk[0] = (short)f2bf(va.x); pk[1] = (short)f2bf(va.y);
            pk[2] = (short)f2bf(va.z); pk[3] = (short)f2bf(va.w);
            pk[4] = (short)f2bf(vb.x); pk[5] = (short)f2bf(vb.y);
            pk[6] = (short)f2bf(vb.z); pk[7] = (short)f2bf(vb.w);
            *(short8v*)((char*)Xs[0] + xfrag_off(row, c8)) = pk;
        }
    }
    __syncthreads();

    int curb = 0;
    for (int i = 0; i < tpb; ++i) {
        const int tile = tile0 + i;
        if (tile >= ntiles) break;
        const bool havenext = (i + 1 < tpb) && (tile + 1 < ntiles);
        const char* XsC = (const char*)Xs[curb];
        char* XsN = (char*)Xs[curb ^ 1];
        const float4* Xg1 = (const float4*)(X + (int64_t)(tile + 1) * 64 * D_IN);

        f32x4 acc[4][2];
        #pragma unroll
        for (int rt = 0; rt < 4; ++rt) {
            acc[rt][0] = (f32x4){0.f, 0.f, 0.f, 0.f};
            acc[rt][1] = (f32x4){0.f, 0.f, 0.f, 0.f};
        }

        // ---- issue first half of next tile's loads (its 0..3) ----
        float4 sA[8];
        if (havenext) {
            #pragma unroll
            for (int it = 0; it < 4; ++it) {
                int g = tid + it * 512;
                int row = g >> 6, c8 = g & 63;
                sA[2 * it + 0] = Xg1[row * 128 + c8 * 2 + 0];
                sA[2 * it + 1] = Xg1[row * 128 + c8 * 2 + 1];
            }
        }

        // ---- quarter 0: ks 0..3 ----
        #pragma unroll
        for (int ks = 0; ks < 4; ++ks) {
            int av = lane16 ^ ((ks & 7) << 4);
            #pragma unroll
            for (int rt = 0; rt < 4; ++rt) {
                short8v a = *(const short8v*)(XsC + (ks * 4 + rt) * 1024 + av);
                acc[rt][0] = __builtin_amdgcn_mfma_f32_16x16x32_bf16(a, B[ks][0], acc[rt][0], 0, 0, 0);
                acc[rt][1] = __builtin_amdgcn_mfma_f32_16x16x32_bf16(a, B[ks][1], acc[rt][1], 0, 0, 0);
            }
        }

        // ---- write half A, issue half B (its 4..7) ----
        float4 sB[8];
        if (havenext) {
            #pragma unroll
            for (int it = 0; it < 4; ++it) {
                int g = tid + it * 512;
                int row = g >> 6, c8 = g & 63;
                float4 va = sA[2 * it + 0], vb = sA[2 * it + 1];
                short8v pk;
                pk[0] = (short)f2bf(va.x); pk[1] = (short)f2bf(va.y);
                pk[2] = (short)f2bf(va.z); pk[3] = (short)f2bf(va.w);
                pk[4] = (short)f2bf(vb.x); pk[5] = (short)f2bf(vb.y);
                pk[6] = (short)f2bf(vb.z); pk[7] = (short)f2bf(vb.w);
                *(short8v*)(XsN + xfrag_off(row, c8)) = pk;
            }
            #pragma unroll
            for (int it = 4; it < 8; ++it) {
                int g = tid + it * 512;
                int row = g >> 6, c8 = g & 63;
                sB[2 * (it - 4) + 0] = Xg1[row * 128 + c8 * 2 + 0];
                sB[2 * (it - 4) + 1] = Xg1[row * 128 + c8 * 2 + 1];
            }
        }

        // ---- quarter 1: ks 4..7 ----
        #pragma unroll
        for (int ks = 4; ks < 8; ++ks) {
            int av = lane16 ^ ((ks & 7) << 4);
            #pragma unroll
            for (int rt = 0; rt < 4; ++rt) {
                short8v a = *(const short8v*)(XsC + (ks * 4 + rt) * 1024 + av);
                acc[rt][0] = __builtin_amdgcn_mfma_f32_16x16x32_bf16(a, B[ks][0], acc[rt][0], 0, 0, 0);
                acc[rt][1] = __builtin_amdgcn_mfma_f32_16x16x32_bf16(a, B[ks][1], acc[rt][1], 0, 0, 0);
            }
        }

        // ---- write half B ----
        if (havenext) {
            #pragma unroll
            for (int it = 4; it < 8; ++it) {
                int g = tid + it * 512;
                int row = g >> 6, c8 = g & 63;
                float4 va = sB[2 * (it - 4) + 0], vb = sB[2 * (it - 4) + 1];
                short8v pk;
                pk[0] = (short)f2bf(va.x); pk[1] = (short)f2bf(va.y);
                pk[2] = (short)f2bf(va.z); pk[3] = (short)f2bf(va.w);
                pk[4] = (short)f2bf(vb.x); pk[5] = (short)f2bf(vb.y);
                pk[6] = (short)f2bf(vb.z); pk[7] = (short)f2bf(vb.w);
                *(short8v*)(XsN + xfrag_off(row, c8)) = pk;
            }
        }

        // ---- quarters 2,3: ks 8..15 ----
        #pragma unroll
        for (int ks = 8; ks < 16; ++ks) {
            int av = lane16 ^ ((ks & 7) << 4);
            #pragma unroll
            for (int rt = 0; rt < 4; ++rt) {
                short8v a = *(const short8v*)(XsC + (ks * 4 + rt) * 1024 + av);
                acc[rt][0] = __builtin_amdgcn_mfma_f32_16x16x32_bf16(a, B[ks][0], acc[rt][0], 0, 0, 0);
                acc[rt][1] = __builtin_amdgcn_mfma_f32_16x16x32_bf16(a, B[ks][1], acc[rt][1], 0, 0, 0);
            }
        }

        // ---- epilogue 1: tanh + u-dot partials, butterfly over 16 col-lanes ----
        float p[4][4];
        #pragma unroll
        for (int rt = 0; rt < 4; ++rt)
            #pragma unroll
            for (int r = 0; r < 4; ++r) {
                float t0 = fast_tanhf(acc[rt][0][r] + bv[0]) * uv[0];
                float t1 = fast_tanhf(acc[rt][1][r] + bv[1]) * uv[1];
                p[rt][r] = t0 + t1;
            }
        #pragma unroll
        for (int m = 1; m < 16; m <<= 1)
            #pragma unroll
            for (int rt = 0; rt < 4; ++rt)
                #pragma unroll
                for (int r = 0; r < 4; ++r)
                    p[rt][r] += __shfl_xor(p[rt][r], m, 64);
        if (lo == 0) {
            #pragma unroll
            for (int rt = 0; rt < 4; ++rt) {
                f32x4 v4 = {p[rt][0], p[rt][1], p[rt][2], p[rt][3]};
                *(f32x4*)&vured[wid][rt * 16 + hi * 4] = v4;
            }
        }
        __syncthreads();

        // ---- epilogue 2: cross-wave vu reduce + softmax over t (quads) ----
        if (tid < 64) {
            float v = 0.f;
            #pragma unroll
            for (int w = 0; w < 8; ++w) v += vured[w][tid];
            float mx = fmaxf(v, __shfl_xor(v, 1, 64));
            mx = fmaxf(mx, __shfl_xor(mx, 2, 64));
            float e = __expf(v - mx);
            float ss = e + __shfl_xor(e, 1, 64);
            ss += __shfl_xor(ss, 2, 64);
            float av = e / ss;
            alsh[tid] = av;
            alph[(int64_t)tile * 64 + tid] = av;
        }
        __syncthreads();

        // ---- epilogue 3: weighted sum from XsC (32 threads/sample) ----
        {
            const int s = tid >> 5, l5 = tid & 31;
            const int rt = s >> 2;
            float a0 = alsh[s * 4 + 0], a1 = alsh[s * 4 + 1];
            float a2 = alsh[s * 4 + 2], a3 = alsh[s * 4 + 3];
            float* outp = out + ((int64_t)tile * 16 + s) * D_IN;
            #pragma unroll
            for (int pp = 0; pp < 2; ++pp) {
                int kg = l5 + pp * 32;           // granule of 8 d's
                int ks = kg >> 2;
                float o[8];
                #pragma unroll
                for (int e = 0; e < 8; ++e) o[e] = 0.f;
                #pragma unroll
                for (int r = 0; r < 4; ++r) {
                    int row = s * 4 + r;
                    int lane_f = (row & 15) + (kg & 3) * 16;
                    int off = (((ks * 4 + rt) * 64 + lane_f) * 16) ^ ((ks & 7) << 4);
                    short8v xq = *(const short8v*)(XsC + off);
                    float ar = (r == 0) ? a0 : (r == 1) ? a1 : (r == 2) ? a2 : a3;
                    #pragma unroll
                    for (int e = 0; e < 8; ++e)
                        o[e] += ar * bf2f((unsigned short)xq[e]);
                }
                float4 o4a = {o[0], o[1], o[2], o[3]};
                float4 o4b = {o[4], o[5], o[6], o[7]};
                *(float4*)(outp + kg * 8 + 0) = o4a;
                *(float4*)(outp + kg * 8 + 4) = o4b;
            }
        }
        __syncthreads();   // stage writes visible; vured/alsh/Xs reusable
        curb ^= 1;
    }
}

// ---------------------------------------------------------------------------
// Fallback (generality): plain fp32, 1 block per sample.
// ---------------------------------------------------------------------------
__global__ void att_fallback(const float* __restrict__ X, const float* __restrict__ W,
                             const float* __restrict__ bb, const float* __restrict__ uu,
                             float* __restrict__ out, float* __restrict__ alph)
{
    const int s = blockIdx.x;
    const int tid = threadIdx.x;                   // 256 threads
    __shared__ float Xsf[2048];
    __shared__ float red[4][4];
    __shared__ float alshf[4];
    for (int i = tid; i < 2048; i += 256) Xsf[i] = X[(size_t)s * 2048 + i];
    __syncthreads();
    float vus[4];
    const int a = tid;
    for (int t = 0; t < 4; ++t) {
        float acc = bb[a];
        for (int d = 0; d < 512; ++d) acc += Xsf[t * 512 + d] * W[d * 256 + a];
        vus[t] = tanhf(acc) * uu[a];
    }
    const int wid = tid >> 6, lane = tid & 63;
    for (int t = 0; t < 4; ++t) {
        float v = vus[t];
        for (int m = 1; m < 64; m <<= 1) v += __shfl_xor(v, m, 64);
        if (lane == 0) red[t][wid] = v;
    }
    __syncthreads();
    if (tid == 0) {
        float vv[4];
        for (int t = 0; t < 4; ++t) vv[t] = red[t][0] + red[t][1] + red[t][2] + red[t][3];
        float mx = fmaxf(fmaxf(vv[0], vv[1]), fmaxf(vv[2], vv[3]));
        float e[4], ssum = 0.f;
        for (int t = 0; t < 4; ++t) { e[t] = expf(vv[t] - mx); ssum += e[t]; }
        for (int t = 0; t < 4; ++t) {
            float av = e[t] / ssum;
            alshf[t] = av;
            alph[(size_t)s * 4 + t] = av;
        }
    }
    __syncthreads();
    for (int d = tid; d < 512; d += 256) {
        float o = 0.f;
        for (int t = 0; t < 4; ++t) o += alshf[t] * Xsf[t * 512 + d];
        out[(size_t)s * 512 + d] = o;
    }
}

// ---------------------------------------------------------------------------
extern "C" void kernel_launch(void* const* d_in, const int* in_sizes, int n_in,
                              void* d_out, int out_size, void* d_ws, size_t ws_size,
                              hipStream_t stream) {
    const float* X = (const float*)d_in[0];
    const float* W = (const float*)d_in[1];
    const float* b = (const float*)d_in[2];
    const float* u = (const float*)d_in[3];
    float* out = (float*)d_out;
    const int N = in_sizes[0] / (4 * D_IN);        // samples
    float* alph = out + (size_t)N * D_IN;

    if (ws_size >= (size_t)D_IN * ATT * sizeof(unsigned short) && (N % 16) == 0) {
        unsigned short* Wf = (unsigned short*)d_ws;
        wconv_kernel<<<(D_IN * ATT) / 256, 256, 0, stream>>>(W, Wf);
        const int ntiles = N / 16;                 // 64-row tiles
        const int grid = ntiles < 512 ? ntiles : 512;
        const int tpb = (ntiles + grid - 1) / grid;
        att_main<<<grid, 512, 0, stream>>>(X, Wf, b, u, out, alph, ntiles, tpb);
    } else {
        att_fallback<<<N, 256, 0, stream>>>(X, W, b, u, out, alph);
    }
}